// Round 1
// baseline (2504.428 us; speedup 1.0000x reference)
//
#include <hip/hip_runtime.h>
#include <hip/hip_bf16.h>

#define N_TEXT 80000
#define NTOT   100000
#define NE     200000
#define EMB    256
#define HID    256
#define VMOT   17
#define MDIM   64
#define KTOK   4

// ---------------- workspace layout (float offsets) ----------------
#define O_INVF 0                    // [NTOT]  1/max(in-degree,1)  (fwd: t side)
#define O_INVR (NTOT)               // [NTOT]  rev: h side
#define O_POS  (2*NTOT)             // [NTOT*10] pos_feat (topic|h1|h2|h3|h4)
#define O_ADJ  (12*NTOT)            // [289]
#define O_HT   (12*NTOT + 512)      // [17*64]
#define O_GATE (12*NTOT + 2048)     // [3]
#define O_CVEC (12*NTOT + 2056)     // [256]  q@pw1[:256] + pb1
#define O_NME  (12*NTOT + 2560)     // [NTOT*64]
#define ZERO_FLOATS (12*NTOT + 2560)

// ---------------- small kernels ----------------
__global__ void k_zero(float* ws, int n) {
  int i = blockIdx.x * blockDim.x + threadIdx.x;
  if (i < n) ws[i] = 0.f;
}

__global__ void k_deg(const int* __restrict__ h_id, const int* __restrict__ t_id,
                      float* __restrict__ ws) {
  int e = blockIdx.x * blockDim.x + threadIdx.x;
  if (e < NE) {
    atomicAdd(&ws[O_INVF + t_id[e]], 1.0f);
    atomicAdd(&ws[O_INVR + h_id[e]], 1.0f);
  }
}

__global__ void k_prep_nodes(const float* __restrict__ topic, float* __restrict__ ws) {
  int n = blockIdx.x * blockDim.x + threadIdx.x;
  if (n < NTOT) {
    float cf = ws[O_INVF + n]; ws[O_INVF + n] = 1.0f / fmaxf(cf, 1.0f);
    float cr = ws[O_INVR + n]; ws[O_INVR + n] = 1.0f / fmaxf(cr, 1.0f);
    ws[O_POS + n*10 + 0] = topic[2*n];
    ws[O_POS + n*10 + 1] = topic[2*n + 1];
  }
}

__global__ void k_dde_scatter(const int* __restrict__ src_id, const int* __restrict__ dst_id,
                              int srcCol, int dstCol, float* __restrict__ ws) {
  int e = blockIdx.x * blockDim.x + threadIdx.x;
  if (e < NE) {
    int s = src_id[e], d = dst_id[e];
    atomicAdd(&ws[O_POS + d*10 + dstCol],     ws[O_POS + s*10 + srcCol]);
    atomicAdd(&ws[O_POS + d*10 + dstCol + 1], ws[O_POS + s*10 + srcCol + 1]);
  }
}

__global__ void k_dde_scale(int col, int invOff, float* __restrict__ ws) {
  int n = blockIdx.x * blockDim.x + threadIdx.x;
  if (n < NTOT) {
    float iv = ws[invOff + n];
    ws[O_POS + n*10 + col]     *= iv;
    ws[O_POS + n*10 + col + 1] *= iv;
  }
}

__global__ void k_adj(const int* __restrict__ tids, const float* __restrict__ twts,
                      float* __restrict__ ws) {
  __shared__ float sadj[VMOT*VMOT];
  for (int i = threadIdx.x; i < VMOT*VMOT; i += blockDim.x) sadj[i] = 0.f;
  __syncthreads();
  int e = blockIdx.x * blockDim.x + threadIdx.x;
  if (e < NE) {
    int id[KTOK]; float w[KTOK];
#pragma unroll
    for (int k = 0; k < KTOK; k++) { id[k] = tids[e*KTOK + k]; w[k] = twts[e*KTOK + k]; }
#pragma unroll
    for (int i = 0; i < KTOK; i++)
#pragma unroll
      for (int j = 0; j < KTOK; j++) {
        float c = w[i] * w[j];
        if (id[i] > 0 && id[j] > 0 && c > 0.f) atomicAdd(&sadj[id[i]*VMOT + id[j]], c);
      }
  }
  __syncthreads();
  for (int i = threadIdx.x; i < VMOT*VMOT; i += blockDim.x) {
    float v = sadj[i];
    if (v != 0.f) atomicAdd(&ws[O_ADJ + i], v);
  }
}

__global__ void k_motif_gnn(const float* __restrict__ mo, const float* __restrict__ gsw,
                            const float* __restrict__ gsb, const float* __restrict__ gmw,
                            const float* __restrict__ gmb, float* __restrict__ ws) {
  __shared__ float A[VMOT*VMOT];
  __shared__ float Bm[VMOT*VMOT];
  __shared__ float inv_row[VMOT];
  __shared__ float smo[VMOT*MDIM];
  __shared__ float sm[VMOT*MDIM];
  int t = threadIdx.x;
  for (int i = t; i < VMOT*VMOT; i += blockDim.x) A[i] = ws[O_ADJ + i];
  for (int i = t; i < VMOT*MDIM; i += blockDim.x) smo[i] = mo[i];
  __syncthreads();
  for (int i = t; i < VMOT*VMOT; i += blockDim.x) {
    int r = i / VMOT, c = i % VMOT;
    float v = 0.5f * (A[i] + A[c*VMOT + r]) + (r == c ? 1.f : 0.f);
    if (r == 0 || c == 0) v = (r == 0 && c == 0) ? 1.f : 0.f;
    Bm[i] = v;
  }
  __syncthreads();
  if (t < VMOT) {
    float s = 0.f;
    for (int c = 0; c < VMOT; c++) s += Bm[t*VMOT + c];
    inv_row[t] = 1.f / fmaxf(s, 1e-8f);
  }
  __syncthreads();
  for (int i = t; i < VMOT*MDIM; i += blockDim.x) {
    int v = i / MDIM, d = i % MDIM;
    float s = 0.f;
    for (int u = 0; u < VMOT; u++) s += Bm[v*VMOT + u] * smo[u*MDIM + d];
    sm[i] = s * inv_row[v];
  }
  __syncthreads();
  for (int i = t; i < VMOT*MDIM; i += blockDim.x) {
    int v = i / MDIM, d = i % MDIM;
    float a = gsb[d] + gmb[d];
    for (int m = 0; m < MDIM; m++)
      a += smo[v*MDIM + m] * gsw[m*MDIM + d] + sm[v*MDIM + m] * gmw[m*MDIM + d];
    ws[O_HT + i] = smo[i] + fmaxf(a, 0.f);
  }
}

__global__ void k_gate_cvec(const float* __restrict__ q, const float* __restrict__ gate_w,
                            const float* __restrict__ gate_b, const float* __restrict__ pw1,
                            const float* __restrict__ pb1, float* __restrict__ ws) {
  __shared__ float sq[EMB];
  __shared__ float red[3];
  int t = threadIdx.x;  // block = 256
  sq[t] = q[t];
  if (t < 3) red[t] = 0.f;
  __syncthreads();
  // cvec[t] = sum_i q[i]*pw1[i][t] + pb1[t]
  float s = pb1[t];
  for (int i = 0; i < EMB; i++) s += sq[i] * pw1[i*HID + t];
  ws[O_CVEC + t] = s;
  atomicAdd(&red[0], sq[t] * gate_w[t*3 + 0]);
  atomicAdd(&red[1], sq[t] * gate_w[t*3 + 1]);
  atomicAdd(&red[2], sq[t] * gate_w[t*3 + 2]);
  __syncthreads();
  if (t == 0) {
    float l0 = red[0] + gate_b[0], l1 = red[1] + gate_b[1], l2 = red[2] + gate_b[2];
    float mx = fmaxf(l0, fmaxf(l1, l2));
    float e0 = expf(l0 - mx), e1 = expf(l1 - mx), e2 = expf(l2 - mx);
    float inv = 1.f / (e0 + e1 + e2);
    ws[O_GATE + 0] = e0 * inv; ws[O_GATE + 1] = e1 * inv; ws[O_GATE + 2] = e2 * inv;
  }
}

__global__ void k_nme(const int* __restrict__ nids, const float* __restrict__ nwts,
                      float* __restrict__ ws) {
  __shared__ float sht[VMOT*MDIM];
  for (int i = threadIdx.x; i < VMOT*MDIM; i += blockDim.x) sht[i] = ws[O_HT + i];
  __syncthreads();
  int gid = blockIdx.x * blockDim.x + threadIdx.x;
  if (gid < NTOT * MDIM) {
    int n = gid >> 6, d = gid & 63;
    float s = 0.f;
#pragma unroll
    for (int k = 0; k < KTOK; k++) {
      int id = nids[n*KTOK + k];
      s += nwts[n*KTOK + k] * sht[id*MDIM + d];
    }
    ws[O_NME + gid] = s;
  }
}

// ---------------- mega edge kernel ----------------
// 64 edges x 256 cols per block; 256 threads; each thread: 8 edges x 8 cols.
// cx = tid&31 -> cols 8*cx..8*cx+7 ; cy = tid>>5 -> edges cy*8..cy*8+7
#define KT 16
#define XP 68   // sXT row stride (floats)
#define FP 264  // sF row stride (bf16)

__device__ __forceinline__ void stageW(float* __restrict__ sW, const float* __restrict__ W,
                                       int row0, int nrows, int tid) {
#pragma unroll
  for (int i = 0; i < 4; i++) {
    int idx4 = tid + i*256;          // 1024 float4 = 16 rows x 256
    int r = idx4 >> 6;
    int c4 = (idx4 & 63) << 2;
    float4 v = make_float4(0.f, 0.f, 0.f, 0.f);
    if (r < nrows) v = *reinterpret_cast<const float4*>(&W[(size_t)(row0 + r)*256 + c4]);
    *reinterpret_cast<float4*>(&sW[r*256 + c4]) = v;
  }
}

__device__ __forceinline__ void fma16(float (&acc)[8][8], const float* __restrict__ sW,
                                      const float* __restrict__ sXT, int cx, int cy) {
#pragma unroll 4
  for (int k = 0; k < KT; k++) {
    const float4 x0 = *reinterpret_cast<const float4*>(&sXT[k*XP + cy*8]);
    const float4 x1 = *reinterpret_cast<const float4*>(&sXT[k*XP + cy*8 + 4]);
    const float4 w0 = *reinterpret_cast<const float4*>(&sW[k*256 + cx*8]);
    const float4 w1 = *reinterpret_cast<const float4*>(&sW[k*256 + cx*8 + 4]);
    const float xs[8] = {x0.x, x0.y, x0.z, x0.w, x1.x, x1.y, x1.z, x1.w};
    const float wv[8] = {w0.x, w0.y, w0.z, w0.w, w1.x, w1.y, w1.z, w1.w};
#pragma unroll
    for (int i = 0; i < 8; i++)
#pragma unroll
      for (int j = 0; j < 8; j++)
        acc[i][j] = fmaf(xs[i], wv[j], acc[i][j]);
  }
}

__global__ __launch_bounds__(256, 2) void k_edge(
    const int* __restrict__ h_id, const int* __restrict__ r_id, const int* __restrict__ t_id,
    const float* __restrict__ ent, const float* __restrict__ rel, const float* __restrict__ nte,
    const int* __restrict__ tr_ids, const float* __restrict__ tr_wts,
    const float* __restrict__ nh_w, const float* __restrict__ nh_b,
    const float* __restrict__ pos_w, const float* __restrict__ pos_b,
    const float* __restrict__ st_w, const float* __restrict__ st_b,
    const float* __restrict__ pw1, const float* __restrict__ pw2,
    const float* __restrict__ pb2,
    const float* __restrict__ ws, float* __restrict__ out) {
  __shared__ float sW[KT*256];                 // 16 KB
  __shared__ float sXT[KT*XP];                 // 4.25 KB (transposed X tile [k][m])
  __shared__ __hip_bfloat16 sFb[64*FP];        // 33.8 KB fused activations
  __shared__ int sh[64], stt[64], sr[64];

  const int tid = threadIdx.x;
  const int cx = tid & 31;
  const int cy = tid >> 5;
  const int e0 = blockIdx.x * 64;

  if (tid < 64) {
    sh[tid]  = h_id[e0 + tid];
    stt[tid] = t_id[e0 + tid];
    sr[tid]  = r_id[e0 + tid];
  }
  const float g0 = ws[O_GATE + 0], g1 = ws[O_GATE + 1], g2 = ws[O_GATE + 2];
  __syncthreads();

  float acc[8][8];
#pragma unroll
  for (int i = 0; i < 8; i++)
#pragma unroll
    for (int j = 0; j < 8; j++) acc[i][j] = 0.f;

  // ---- phase A: h_nbr, K = 640 = [h_e[h]|h_e[t]|nme[h]|nme[t]] ----
  for (int kt = 0; kt < 640; kt += KT) {
    stageW(sW, nh_w, kt, KT, tid);
#pragma unroll
    for (int i = 0; i < 4; i++) {
      int idx = i*256 + tid;           // 64 edges x 16 k
      int k = idx & 15, m = idx >> 4;
      int kk = kt + k;
      int h = sh[m], t = stt[m];
      float v;
      if (kk < 256)      v = (h < N_TEXT) ? ent[(size_t)h*256 + kk] : nte[kk];
      else if (kk < 512) { int k2 = kk - 256; v = (t < N_TEXT) ? ent[(size_t)t*256 + k2] : nte[k2]; }
      else if (kk < 576) v = ws[O_NME + h*64 + (kk - 512)];
      else               v = ws[O_NME + t*64 + (kk - 576)];
      sXT[k*XP + m] = v;
    }
    __syncthreads();
    fma16(acc, sW, sXT, cx, cy);
    __syncthreads();
  }
  {
    const float4 b0 = *reinterpret_cast<const float4*>(&nh_b[cx*8]);
    const float4 b1 = *reinterpret_cast<const float4*>(&nh_b[cx*8 + 4]);
    const float bb[8] = {b0.x, b0.y, b0.z, b0.w, b1.x, b1.y, b1.z, b1.w};
#pragma unroll
    for (int i = 0; i < 8; i++) {
      int base = (cy*8 + i)*FP + cx*8;
#pragma unroll
      for (int j = 0; j < 8; j++) {
        sFb[base + j] = __float2bfloat16(g0 * fmaxf(acc[i][j] + bb[j], 0.f));
        acc[i][j] = 0.f;
      }
    }
  }

  // ---- phase B: h_pos, K = 20 = [pos_feat[h]|pos_feat[t]] ----
  for (int kt = 0; kt < 32; kt += KT) {
    stageW(sW, pos_w, kt, (kt == 0) ? KT : (20 - KT), tid);
#pragma unroll
    for (int i = 0; i < 4; i++) {
      int idx = i*256 + tid;
      int k = idx & 15, m = idx >> 4;
      int kk = kt + k;
      float v = 0.f;
      if (kk < 20) {
        int nid = (kk < 10) ? sh[m] : stt[m];
        int c = (kk < 10) ? kk : kk - 10;
        v = ws[O_POS + nid*10 + c];
      }
      sXT[k*XP + m] = v;
    }
    __syncthreads();
    fma16(acc, sW, sXT, cx, cy);
    __syncthreads();
  }
  {
    const float4 b0 = *reinterpret_cast<const float4*>(&pos_b[cx*8]);
    const float4 b1 = *reinterpret_cast<const float4*>(&pos_b[cx*8 + 4]);
    const float bb[8] = {b0.x, b0.y, b0.z, b0.w, b1.x, b1.y, b1.z, b1.w};
#pragma unroll
    for (int i = 0; i < 8; i++) {
      int base = (cy*8 + i)*FP + cx*8;
#pragma unroll
      for (int j = 0; j < 8; j++) {
        float old = __bfloat162float(sFb[base + j]);
        sFb[base + j] = __float2bfloat16(old + g1 * fmaxf(acc[i][j] + bb[j], 0.f));
        acc[i][j] = 0.f;
      }
    }
  }

  // ---- phase C: h_str, K = 320 = [rel[r]|triple_motif_emb] ----
  for (int kt = 0; kt < 320; kt += KT) {
    stageW(sW, st_w, kt, KT, tid);
#pragma unroll
    for (int i = 0; i < 4; i++) {
      int idx = i*256 + tid;
      int k = idx & 15, m = idx >> 4;
      int kk = kt + k;
      float v;
      if (kk < 256) v = rel[(size_t)sr[m]*256 + kk];
      else {
        int d = kk - 256;
        int eb = (e0 + m)*KTOK;
        v = 0.f;
#pragma unroll
        for (int k2 = 0; k2 < KTOK; k2++) {
          int id = tr_ids[eb + k2];
          v += tr_wts[eb + k2] * ws[O_HT + id*64 + d];
        }
      }
      sXT[k*XP + m] = v;
    }
    __syncthreads();
    fma16(acc, sW, sXT, cx, cy);
    __syncthreads();
  }
  {
    const float4 b0 = *reinterpret_cast<const float4*>(&st_b[cx*8]);
    const float4 b1 = *reinterpret_cast<const float4*>(&st_b[cx*8 + 4]);
    const float bb[8] = {b0.x, b0.y, b0.z, b0.w, b1.x, b1.y, b1.z, b1.w};
#pragma unroll
    for (int i = 0; i < 8; i++) {
      int base = (cy*8 + i)*FP + cx*8;
#pragma unroll
      for (int j = 0; j < 8; j++) {
        float old = __bfloat162float(sFb[base + j]);
        sFb[base + j] = __float2bfloat16(old + g2 * fmaxf(acc[i][j] + bb[j], 0.f));
        acc[i][j] = 0.f;
      }
    }
  }

  // ---- phase D: hidden = fused @ pw1[256:512] (cvec added in E) ----
  for (int kt = 0; kt < 256; kt += KT) {
    stageW(sW, pw1, 256 + kt, KT, tid);
    __syncthreads();
#pragma unroll 2
    for (int k = 0; k < KT; k++) {
      const float4 w0 = *reinterpret_cast<const float4*>(&sW[k*256 + cx*8]);
      const float4 w1 = *reinterpret_cast<const float4*>(&sW[k*256 + cx*8 + 4]);
      const float wv[8] = {w0.x, w0.y, w0.z, w0.w, w1.x, w1.y, w1.z, w1.w};
#pragma unroll
      for (int i = 0; i < 8; i++) {
        float x = __bfloat162float(sFb[(cy*8 + i)*FP + kt + k]);
#pragma unroll
        for (int j = 0; j < 8; j++)
          acc[i][j] = fmaf(x, wv[j], acc[i][j]);
      }
    }
    __syncthreads();
  }

  // ---- phase E: out = relu(hidden + cvec) @ pw2 + pb2 ----
  {
    const float4 c0 = *reinterpret_cast<const float4*>(&ws[O_CVEC + cx*8]);
    const float4 c1 = *reinterpret_cast<const float4*>(&ws[O_CVEC + cx*8 + 4]);
    const float4 p0 = *reinterpret_cast<const float4*>(&pw2[cx*8]);
    const float4 p1 = *reinterpret_cast<const float4*>(&pw2[cx*8 + 4]);
    const float cvv[8] = {c0.x, c0.y, c0.z, c0.w, c1.x, c1.y, c1.z, c1.w};
    const float p2v[8] = {p0.x, p0.y, p0.z, p0.w, p1.x, p1.y, p1.z, p1.w};
    const float pb2v = pb2[0];
    float p[8];
#pragma unroll
    for (int i = 0; i < 8; i++) {
      float s = 0.f;
#pragma unroll
      for (int j = 0; j < 8; j++)
        s += fmaxf(acc[i][j] + cvv[j], 0.f) * p2v[j];
      p[i] = s;
    }
#pragma unroll
    for (int off = 16; off > 0; off >>= 1)
#pragma unroll
      for (int i = 0; i < 8; i++) p[i] += __shfl_down(p[i], off, 64);
    if (cx == 0) {
#pragma unroll
      for (int i = 0; i < 8; i++) out[e0 + cy*8 + i] = p[i] + pb2v;
    }
  }
}

// ---------------- launch ----------------
extern "C" void kernel_launch(void* const* d_in, const int* in_sizes, int n_in,
                              void* d_out, int out_size, void* d_ws, size_t ws_size,
                              hipStream_t stream) {
  (void)in_sizes; (void)n_in; (void)out_size; (void)ws_size;
  const int*   h_id   = (const int*)  d_in[0];
  const int*   r_id   = (const int*)  d_in[1];
  const int*   t_id   = (const int*)  d_in[2];
  const float* q      = (const float*)d_in[3];
  const float* ent    = (const float*)d_in[4];
  const float* rel    = (const float*)d_in[6];
  const float* topic  = (const float*)d_in[7];
  const int*   nids   = (const int*)  d_in[8];
  const float* nwts   = (const float*)d_in[9];
  const int*   tids   = (const int*)  d_in[10];
  const float* twts   = (const float*)d_in[11];
  const float* nte    = (const float*)d_in[12];
  const float* mo     = (const float*)d_in[13];
  const float* gsw    = (const float*)d_in[14];
  const float* gsb    = (const float*)d_in[15];
  const float* gmw    = (const float*)d_in[16];
  const float* gmb    = (const float*)d_in[17];
  const float* nh_w   = (const float*)d_in[18];
  const float* nh_b   = (const float*)d_in[19];
  const float* pos_w  = (const float*)d_in[20];
  const float* pos_b  = (const float*)d_in[21];
  const float* st_w   = (const float*)d_in[22];
  const float* st_b   = (const float*)d_in[23];
  const float* gate_w = (const float*)d_in[24];
  const float* gate_b = (const float*)d_in[25];
  const float* pw1    = (const float*)d_in[26];
  const float* pb1    = (const float*)d_in[27];
  const float* pw2    = (const float*)d_in[28];
  const float* pb2    = (const float*)d_in[29];
  float* ws  = (float*)d_ws;
  float* out = (float*)d_out;

  k_zero<<<(ZERO_FLOATS + 255)/256, 256, 0, stream>>>(ws, ZERO_FLOATS);
  k_deg<<<(NE + 255)/256, 256, 0, stream>>>(h_id, t_id, ws);
  k_prep_nodes<<<(NTOT + 255)/256, 256, 0, stream>>>(topic, ws);
  // DDE rounds: fwd uses (src=h, dst=t, inv_fwd); rev uses (src=t, dst=h, inv_rev)
  k_dde_scatter<<<(NE + 255)/256, 256, 0, stream>>>(h_id, t_id, 0, 2, ws);
  k_dde_scale  <<<(NTOT + 255)/256, 256, 0, stream>>>(2, O_INVF, ws);
  k_dde_scatter<<<(NE + 255)/256, 256, 0, stream>>>(h_id, t_id, 2, 4, ws);
  k_dde_scale  <<<(NTOT + 255)/256, 256, 0, stream>>>(4, O_INVF, ws);
  k_dde_scatter<<<(NE + 255)/256, 256, 0, stream>>>(t_id, h_id, 0, 6, ws);
  k_dde_scale  <<<(NTOT + 255)/256, 256, 0, stream>>>(6, O_INVR, ws);
  k_dde_scatter<<<(NE + 255)/256, 256, 0, stream>>>(t_id, h_id, 6, 8, ws);
  k_dde_scale  <<<(NTOT + 255)/256, 256, 0, stream>>>(8, O_INVR, ws);
  k_adj<<<(NE + 255)/256, 256, 0, stream>>>(tids, twts, ws);
  k_motif_gnn<<<1, 256, 0, stream>>>(mo, gsw, gsb, gmw, gmb, ws);
  k_gate_cvec<<<1, 256, 0, stream>>>(q, gate_w, gate_b, pw1, pb1, ws);
  k_nme<<<(NTOT*MDIM + 255)/256, 256, 0, stream>>>(nids, nwts, ws);
  k_edge<<<NE/64, 256, 0, stream>>>(h_id, r_id, t_id, ent, rel, nte, tids, twts,
                                    nh_w, nh_b, pos_w, pos_b, st_w, st_b,
                                    pw1, pw2, pb2, ws, out);
}

// Round 2
// 809.298 us; speedup vs baseline: 3.0946x; 3.0946x over previous
//
#include <hip/hip_runtime.h>
#include <hip/hip_bf16.h>

#define N_TEXT 80000
#define NTOT   100000
#define NE     200000
#define EMB    256
#define HID    256
#define VMOT   17
#define MDIM   64
#define KTOK   4

typedef unsigned short u16;
typedef short short8 __attribute__((ext_vector_type(8)));
typedef float f32x4 __attribute__((ext_vector_type(4)));

// ---------------- workspace layout (float offsets) ----------------
#define O_INVF 0                    // [NTOT]
#define O_INVR (NTOT)               // [NTOT]
#define O_POS  (2*NTOT)             // [NTOT*10]
#define O_ADJ  (12*NTOT)            // [289]
#define O_HT   (12*NTOT + 512)     // [17*64]
#define O_GATE (12*NTOT + 2048)    // [3]
#define O_CVEC (12*NTOT + 2056)    // [256]
#define O_NME  (12*NTOT + 2560)    // [NTOT*64] fp32
#define ZERO_FLOATS (12*NTOT + 2560)
// bf16 transposed weights (u16 stored in float slots, 2 per float)
#define O_WTA (O_NME + NTOT*64)            // 256x640 bf16
#define O_WTB (O_WTA + (256*640)/2)        // 256x32  bf16
#define O_WTC (O_WTB + (256*32)/2)         // 256x320 bf16
#define O_WTD (O_WTC + (256*320)/2)        // 256x256 bf16

#define SZ_A (256*640)
#define SZ_B (256*32)
#define SZ_C (256*320)
#define SZ_D (256*256)
#define SZ_W (SZ_A + SZ_B + SZ_C + SZ_D)

__device__ __forceinline__ u16 f2b(float f) {            // fp32 -> bf16 RNE
  unsigned u = __float_as_uint(f);
  return (u16)((u + 0x7fffu + ((u >> 16) & 1u)) >> 16);
}

__device__ __forceinline__ short8 pack8(const float* f) {
  short8 v;
#pragma unroll
  for (int j = 0; j < 8; j++) v[j] = (short)f2b(f[j]);
  return v;
}

// ---------------- small kernels (validated round 1) ----------------
__global__ void k_zero(float* ws, int n) {
  int i = blockIdx.x * blockDim.x + threadIdx.x;
  if (i < n) ws[i] = 0.f;
}

__global__ void k_deg(const int* __restrict__ h_id, const int* __restrict__ t_id,
                      float* __restrict__ ws) {
  int e = blockIdx.x * blockDim.x + threadIdx.x;
  if (e < NE) {
    atomicAdd(&ws[O_INVF + t_id[e]], 1.0f);
    atomicAdd(&ws[O_INVR + h_id[e]], 1.0f);
  }
}

__global__ void k_prep_nodes(const float* __restrict__ topic, float* __restrict__ ws) {
  int n = blockIdx.x * blockDim.x + threadIdx.x;
  if (n < NTOT) {
    float cf = ws[O_INVF + n]; ws[O_INVF + n] = 1.0f / fmaxf(cf, 1.0f);
    float cr = ws[O_INVR + n]; ws[O_INVR + n] = 1.0f / fmaxf(cr, 1.0f);
    ws[O_POS + n*10 + 0] = topic[2*n];
    ws[O_POS + n*10 + 1] = topic[2*n + 1];
  }
}

__global__ void k_dde_scatter(const int* __restrict__ src_id, const int* __restrict__ dst_id,
                              int srcCol, int dstCol, float* __restrict__ ws) {
  int e = blockIdx.x * blockDim.x + threadIdx.x;
  if (e < NE) {
    int s = src_id[e], d = dst_id[e];
    atomicAdd(&ws[O_POS + d*10 + dstCol],     ws[O_POS + s*10 + srcCol]);
    atomicAdd(&ws[O_POS + d*10 + dstCol + 1], ws[O_POS + s*10 + srcCol + 1]);
  }
}

__global__ void k_dde_scale(int col, int invOff, float* __restrict__ ws) {
  int n = blockIdx.x * blockDim.x + threadIdx.x;
  if (n < NTOT) {
    float iv = ws[invOff + n];
    ws[O_POS + n*10 + col]     *= iv;
    ws[O_POS + n*10 + col + 1] *= iv;
  }
}

__global__ void k_adj(const int* __restrict__ tids, const float* __restrict__ twts,
                      float* __restrict__ ws) {
  __shared__ float sadj[VMOT*VMOT];
  for (int i = threadIdx.x; i < VMOT*VMOT; i += blockDim.x) sadj[i] = 0.f;
  __syncthreads();
  int e = blockIdx.x * blockDim.x + threadIdx.x;
  if (e < NE) {
    int id[KTOK]; float w[KTOK];
#pragma unroll
    for (int k = 0; k < KTOK; k++) { id[k] = tids[e*KTOK + k]; w[k] = twts[e*KTOK + k]; }
#pragma unroll
    for (int i = 0; i < KTOK; i++)
#pragma unroll
      for (int j = 0; j < KTOK; j++) {
        float c = w[i] * w[j];
        if (id[i] > 0 && id[j] > 0 && c > 0.f) atomicAdd(&sadj[id[i]*VMOT + id[j]], c);
      }
  }
  __syncthreads();
  for (int i = threadIdx.x; i < VMOT*VMOT; i += blockDim.x) {
    float v = sadj[i];
    if (v != 0.f) atomicAdd(&ws[O_ADJ + i], v);
  }
}

__global__ void k_motif_gnn(const float* __restrict__ mo, const float* __restrict__ gsw,
                            const float* __restrict__ gsb, const float* __restrict__ gmw,
                            const float* __restrict__ gmb, float* __restrict__ ws) {
  __shared__ float A[VMOT*VMOT];
  __shared__ float Bm[VMOT*VMOT];
  __shared__ float inv_row[VMOT];
  __shared__ float smo[VMOT*MDIM];
  __shared__ float sm[VMOT*MDIM];
  int t = threadIdx.x;
  for (int i = t; i < VMOT*VMOT; i += blockDim.x) A[i] = ws[O_ADJ + i];
  for (int i = t; i < VMOT*MDIM; i += blockDim.x) smo[i] = mo[i];
  __syncthreads();
  for (int i = t; i < VMOT*VMOT; i += blockDim.x) {
    int r = i / VMOT, c = i % VMOT;
    float v = 0.5f * (A[i] + A[c*VMOT + r]) + (r == c ? 1.f : 0.f);
    if (r == 0 || c == 0) v = (r == 0 && c == 0) ? 1.f : 0.f;
    Bm[i] = v;
  }
  __syncthreads();
  if (t < VMOT) {
    float s = 0.f;
    for (int c = 0; c < VMOT; c++) s += Bm[t*VMOT + c];
    inv_row[t] = 1.f / fmaxf(s, 1e-8f);
  }
  __syncthreads();
  for (int i = t; i < VMOT*MDIM; i += blockDim.x) {
    int v = i / MDIM, d = i % MDIM;
    float s = 0.f;
    for (int u = 0; u < VMOT; u++) s += Bm[v*VMOT + u] * smo[u*MDIM + d];
    sm[i] = s * inv_row[v];
  }
  __syncthreads();
  for (int i = t; i < VMOT*MDIM; i += blockDim.x) {
    int v = i / MDIM, d = i % MDIM;
    float a = gsb[d] + gmb[d];
    for (int m = 0; m < MDIM; m++)
      a += smo[v*MDIM + m] * gsw[m*MDIM + d] + sm[v*MDIM + m] * gmw[m*MDIM + d];
    ws[O_HT + i] = smo[i] + fmaxf(a, 0.f);
  }
}

__global__ void k_gate_cvec(const float* __restrict__ q, const float* __restrict__ gate_w,
                            const float* __restrict__ gate_b, const float* __restrict__ pw1,
                            const float* __restrict__ pb1, float* __restrict__ ws) {
  __shared__ float sq[EMB];
  __shared__ float red[3];
  int t = threadIdx.x;  // block = 256
  sq[t] = q[t];
  if (t < 3) red[t] = 0.f;
  __syncthreads();
  float s = pb1[t];
  for (int i = 0; i < EMB; i++) s += sq[i] * pw1[i*HID + t];
  ws[O_CVEC + t] = s;
  atomicAdd(&red[0], sq[t] * gate_w[t*3 + 0]);
  atomicAdd(&red[1], sq[t] * gate_w[t*3 + 1]);
  atomicAdd(&red[2], sq[t] * gate_w[t*3 + 2]);
  __syncthreads();
  if (t == 0) {
    float l0 = red[0] + gate_b[0], l1 = red[1] + gate_b[1], l2 = red[2] + gate_b[2];
    float mx = fmaxf(l0, fmaxf(l1, l2));
    float e0 = expf(l0 - mx), e1 = expf(l1 - mx), e2 = expf(l2 - mx);
    float inv = 1.f / (e0 + e1 + e2);
    ws[O_GATE + 0] = e0 * inv; ws[O_GATE + 1] = e1 * inv; ws[O_GATE + 2] = e2 * inv;
  }
}

__global__ void k_nme(const int* __restrict__ nids, const float* __restrict__ nwts,
                      float* __restrict__ ws) {
  __shared__ float sht[VMOT*MDIM];
  for (int i = threadIdx.x; i < VMOT*MDIM; i += blockDim.x) sht[i] = ws[O_HT + i];
  __syncthreads();
  int gid = blockIdx.x * blockDim.x + threadIdx.x;
  if (gid < NTOT * MDIM) {
    int n = gid >> 6, d = gid & 63;
    float s = 0.f;
#pragma unroll
    for (int k = 0; k < KTOK; k++) {
      int id = nids[n*KTOK + k];
      s += nwts[n*KTOK + k] * sht[id*MDIM + d];
    }
    ws[O_NME + gid] = s;
  }
}

// Pre-transpose all weights to bf16 Wt[n][k]
__global__ void k_prep_w(const float* __restrict__ nh_w, const float* __restrict__ pos_w,
                         const float* __restrict__ st_w, const float* __restrict__ pw1,
                         float* __restrict__ ws) {
  int i = blockIdx.x * blockDim.x + threadIdx.x;
  if (i < SZ_A) {
    int n = i / 640, k = i % 640;
    ((u16*)(ws + O_WTA))[i] = f2b(nh_w[k*256 + n]);
  } else if (i < SZ_A + SZ_B) {
    int j = i - SZ_A; int n = j / 32, k = j % 32;
    float v = 0.f;
    if (k < 10) v = pos_w[k*256 + n];
    else if (k >= 16 && k < 26) v = pos_w[(k - 6)*256 + n];
    ((u16*)(ws + O_WTB))[j] = f2b(v);
  } else if (i < SZ_A + SZ_B + SZ_C) {
    int j = i - SZ_A - SZ_B; int n = j / 320, k = j % 320;
    ((u16*)(ws + O_WTC))[j] = f2b(st_w[k*256 + n]);
  } else if (i < SZ_W) {
    int j = i - SZ_A - SZ_B - SZ_C; int n = j / 256, k = j % 256;
    ((u16*)(ws + O_WTD))[j] = f2b(pw1[(256 + k)*256 + n]);
  }
}

// ---------------- MFMA edge kernel ----------------
// 64 edges x 256 cols per block, 4 waves; wave w -> cols w*64..w*64+63.
// LDS strides padded (+8 bf16) so b128 frag reads alias <=2-way (free, m136).
#define SXS 40
#define SWS 40
#define SFS 264

__device__ __forceinline__ void stage_sW(u16* __restrict__ sW, const u16* __restrict__ Wt,
                                         int Ktot, int kc, int tid) {
#pragma unroll
  for (int i = 0; i < 4; i++) {
    int idx = i*256 + tid;
    int n = idx >> 2, ks = idx & 3;
    short8 v = *reinterpret_cast<const short8*>(&Wt[n*Ktot + kc + ks*8]);
    *reinterpret_cast<short8*>(&sW[n*SWS + ks*8]) = v;
  }
}

__device__ __forceinline__ void mfma_step(f32x4 (&acc)[4][4], const u16* __restrict__ sX,
                                          const u16* __restrict__ sW, int cb, int lm, int lq) {
  short8 a[4], b[4];
#pragma unroll
  for (int mt = 0; mt < 4; mt++)
    a[mt] = *reinterpret_cast<const short8*>(&sX[(mt*16 + lm)*SXS + lq*8]);
#pragma unroll
  for (int nt = 0; nt < 4; nt++)
    b[nt] = *reinterpret_cast<const short8*>(&sW[(cb + nt*16 + lm)*SWS + lq*8]);
#pragma unroll
  for (int mt = 0; mt < 4; mt++)
#pragma unroll
    for (int nt = 0; nt < 4; nt++)
      acc[mt][nt] = __builtin_amdgcn_mfma_f32_16x16x32_bf16(a[mt], b[nt], acc[mt][nt], 0, 0, 0);
}

__global__ __launch_bounds__(256, 2) void k_edge_mfma(
    const int* __restrict__ h_id, const int* __restrict__ r_id, const int* __restrict__ t_id,
    const float* __restrict__ ent, const float* __restrict__ rel, const float* __restrict__ nte,
    const int* __restrict__ tids, const float* __restrict__ twts,
    const float* __restrict__ nh_b, const float* __restrict__ pos_b,
    const float* __restrict__ st_b, const float* __restrict__ pw2,
    const float* __restrict__ pb2,
    const float* __restrict__ ws, float* __restrict__ out) {
  __shared__ __align__(16) u16 sX[64*SXS];    // 5.0 KB
  __shared__ __align__(16) u16 sW[256*SWS];   // 20.0 KB
  __shared__ __align__(16) u16 sF[64*SFS];    // 33.0 KB
  __shared__ float sOut[64];
  __shared__ int sh[64], stt[64], sr[64];

  const int tid = threadIdx.x;
  const int wv = tid >> 6, ln = tid & 63;
  const int lm = ln & 15, lq = ln >> 4;
  const int cb = wv * 64;
  const int e0 = blockIdx.x * 64;

  if (tid < 64) {
    sh[tid]  = h_id[e0 + tid];
    stt[tid] = t_id[e0 + tid];
    sr[tid]  = r_id[e0 + tid];
    sOut[tid] = 0.f;
  }
  const float g0 = ws[O_GATE + 0], g1 = ws[O_GATE + 1], g2 = ws[O_GATE + 2];
  const u16* WA = (const u16*)(ws + O_WTA);
  const u16* WB = (const u16*)(ws + O_WTB);
  const u16* WC = (const u16*)(ws + O_WTC);
  const u16* WD = (const u16*)(ws + O_WTD);
  __syncthreads();

  const int srow = tid >> 2, sks = tid & 3;  // staging: row 0..63, 8-k segment 0..3

  f32x4 acc[4][4];
  float fused[4][4][4];
#pragma unroll
  for (int mt = 0; mt < 4; mt++)
#pragma unroll
    for (int nt = 0; nt < 4; nt++) {
      acc[mt][nt] = (f32x4){0.f, 0.f, 0.f, 0.f};
#pragma unroll
      for (int r = 0; r < 4; r++) fused[mt][nt][r] = 0.f;
    }

  // ---- phase A: h_nbr, K=640 = [h_e[h] | h_e[t] | nme[h] | nme[t]] ----
  for (int kc = 0; kc < 640; kc += 32) {
    {
      int kk = kc + sks*8;
      const float* src;
      if (kk < 512) {
        int node = (kk < 256) ? sh[srow] : stt[srow];
        int k2 = kk & 255;
        src = (node < N_TEXT) ? &ent[node*256 + k2] : &nte[k2];
      } else {
        int node = (kk < 576) ? sh[srow] : stt[srow];
        int k2 = (kk - 512) & 63;
        src = &ws[O_NME + node*64 + k2];
      }
      float4 a0 = *reinterpret_cast<const float4*>(src);
      float4 a1 = *reinterpret_cast<const float4*>(src + 4);
      float f[8] = {a0.x, a0.y, a0.z, a0.w, a1.x, a1.y, a1.z, a1.w};
      *reinterpret_cast<short8*>(&sX[srow*SXS + sks*8]) = pack8(f);
    }
    stage_sW(sW, WA, 640, kc, tid);
    __syncthreads();
    mfma_step(acc, sX, sW, cb, lm, lq);
    __syncthreads();
  }
#pragma unroll
  for (int nt = 0; nt < 4; nt++) {
    float bb = nh_b[cb + nt*16 + lm];
#pragma unroll
    for (int mt = 0; mt < 4; mt++)
#pragma unroll
      for (int r = 0; r < 4; r++) {
        fused[mt][nt][r] += g0 * fmaxf(acc[mt][nt][r] + bb, 0.f);
        acc[mt][nt][r] = 0.f;
      }
  }

  // ---- phase B: h_pos, K=32 = [pos[h](10) pad6 | pos[t](10) pad6] ----
  {
    int node_h = sh[srow], node_t = stt[srow];
    float f[8];
#pragma unroll
    for (int j = 0; j < 8; j++) {
      int kk = sks*8 + j;
      float v = 0.f;
      if (kk < 10) v = ws[O_POS + node_h*10 + kk];
      else if (kk >= 16 && kk < 26) v = ws[O_POS + node_t*10 + kk - 16];
      f[j] = v;
    }
    *reinterpret_cast<short8*>(&sX[srow*SXS + sks*8]) = pack8(f);
    stage_sW(sW, WB, 32, 0, tid);
    __syncthreads();
    mfma_step(acc, sX, sW, cb, lm, lq);
    __syncthreads();
  }
#pragma unroll
  for (int nt = 0; nt < 4; nt++) {
    float bb = pos_b[cb + nt*16 + lm];
#pragma unroll
    for (int mt = 0; mt < 4; mt++)
#pragma unroll
      for (int r = 0; r < 4; r++) {
        fused[mt][nt][r] += g1 * fmaxf(acc[mt][nt][r] + bb, 0.f);
        acc[mt][nt][r] = 0.f;
      }
  }

  // ---- phase C: h_str, K=320 = [rel[r] | triple_motif_emb] ----
  for (int kc = 0; kc < 320; kc += 32) {
    {
      int kk = kc + sks*8;
      float f[8];
      if (kk < 256) {
        const float* src = &rel[sr[srow]*256 + kk];
        float4 a0 = *reinterpret_cast<const float4*>(src);
        float4 a1 = *reinterpret_cast<const float4*>(src + 4);
        f[0]=a0.x; f[1]=a0.y; f[2]=a0.z; f[3]=a0.w;
        f[4]=a1.x; f[5]=a1.y; f[6]=a1.z; f[7]=a1.w;
      } else {
        int d0 = kk - 256;
        int eb = (e0 + srow)*KTOK;
#pragma unroll
        for (int j = 0; j < 8; j++) f[j] = 0.f;
#pragma unroll
        for (int tk = 0; tk < KTOK; tk++) {
          int id = tids[eb + tk]; float w = twts[eb + tk];
          const float* hp = &ws[O_HT + id*64 + d0];
#pragma unroll
          for (int j = 0; j < 8; j++) f[j] += w * hp[j];
        }
      }
      *reinterpret_cast<short8*>(&sX[srow*SXS + sks*8]) = pack8(f);
    }
    stage_sW(sW, WC, 320, kc, tid);
    __syncthreads();
    mfma_step(acc, sX, sW, cb, lm, lq);
    __syncthreads();
  }
#pragma unroll
  for (int nt = 0; nt < 4; nt++) {
    float bb = st_b[cb + nt*16 + lm];
#pragma unroll
    for (int mt = 0; mt < 4; mt++)
#pragma unroll
      for (int r = 0; r < 4; r++) {
        fused[mt][nt][r] += g2 * fmaxf(acc[mt][nt][r] + bb, 0.f);
        acc[mt][nt][r] = 0.f;
      }
  }

  // ---- transpose fused (C-layout) -> sF (A-layout source) ----
#pragma unroll
  for (int mt = 0; mt < 4; mt++)
#pragma unroll
    for (int nt = 0; nt < 4; nt++) {
      int col = cb + nt*16 + lm;
#pragma unroll
      for (int r = 0; r < 4; r++)
        sF[(mt*16 + lq*4 + r)*SFS + col] = f2b(fused[mt][nt][r]);
    }

  // ---- phase D: hidden_pre = fused @ pw1[256:512] ----
  for (int kc = 0; kc < 256; kc += 32) {
    stage_sW(sW, WD, 256, kc, tid);
    __syncthreads();
    short8 a[4], b[4];
#pragma unroll
    for (int mt = 0; mt < 4; mt++)
      a[mt] = *reinterpret_cast<const short8*>(&sF[(mt*16 + lm)*SFS + kc + lq*8]);
#pragma unroll
    for (int nt = 0; nt < 4; nt++)
      b[nt] = *reinterpret_cast<const short8*>(&sW[(cb + nt*16 + lm)*SWS + lq*8]);
#pragma unroll
    for (int mt = 0; mt < 4; mt++)
#pragma unroll
      for (int nt = 0; nt < 4; nt++)
        acc[mt][nt] = __builtin_amdgcn_mfma_f32_16x16x32_bf16(a[mt], b[nt], acc[mt][nt], 0, 0, 0);
    __syncthreads();
  }

  // ---- epilogue: out = relu(hidden_pre + cvec) @ pw2 + pb2 ----
  {
    float cv[4], p2[4];
#pragma unroll
    for (int nt = 0; nt < 4; nt++) {
      int col = cb + nt*16 + lm;
      cv[nt] = ws[O_CVEC + col];
      p2[nt] = pw2[col];
    }
#pragma unroll
    for (int mt = 0; mt < 4; mt++)
#pragma unroll
      for (int r = 0; r < 4; r++) {
        float s = 0.f;
#pragma unroll
        for (int nt = 0; nt < 4; nt++)
          s += fmaxf(acc[mt][nt][r] + cv[nt], 0.f) * p2[nt];
#pragma unroll
        for (int off = 1; off < 16; off <<= 1)
          s += __shfl_xor(s, off, 64);
        if (lm == 0) atomicAdd(&sOut[mt*16 + lq*4 + r], s);
      }
  }
  __syncthreads();
  if (tid < 64) out[e0 + tid] = sOut[tid] + pb2[0];
}

// ---------------- launch ----------------
extern "C" void kernel_launch(void* const* d_in, const int* in_sizes, int n_in,
                              void* d_out, int out_size, void* d_ws, size_t ws_size,
                              hipStream_t stream) {
  (void)in_sizes; (void)n_in; (void)out_size; (void)ws_size;
  const int*   h_id   = (const int*)  d_in[0];
  const int*   r_id   = (const int*)  d_in[1];
  const int*   t_id   = (const int*)  d_in[2];
  const float* q      = (const float*)d_in[3];
  const float* ent    = (const float*)d_in[4];
  const float* rel    = (const float*)d_in[6];
  const float* topic  = (const float*)d_in[7];
  const int*   nids   = (const int*)  d_in[8];
  const float* nwts   = (const float*)d_in[9];
  const int*   tids   = (const int*)  d_in[10];
  const float* twts   = (const float*)d_in[11];
  const float* nte    = (const float*)d_in[12];
  const float* mo     = (const float*)d_in[13];
  const float* gsw    = (const float*)d_in[14];
  const float* gsb    = (const float*)d_in[15];
  const float* gmw    = (const float*)d_in[16];
  const float* gmb    = (const float*)d_in[17];
  const float* nh_w   = (const float*)d_in[18];
  const float* nh_b   = (const float*)d_in[19];
  const float* pos_w  = (const float*)d_in[20];
  const float* pos_b  = (const float*)d_in[21];
  const float* st_w   = (const float*)d_in[22];
  const float* st_b   = (const float*)d_in[23];
  const float* gate_w = (const float*)d_in[24];
  const float* gate_b = (const float*)d_in[25];
  const float* pw1    = (const float*)d_in[26];
  const float* pb1    = (const float*)d_in[27];
  const float* pw2    = (const float*)d_in[28];
  const float* pb2    = (const float*)d_in[29];
  float* ws  = (float*)d_ws;
  float* out = (float*)d_out;

  k_zero<<<(ZERO_FLOATS + 255)/256, 256, 0, stream>>>(ws, ZERO_FLOATS);
  k_prep_w<<<(SZ_W + 255)/256, 256, 0, stream>>>(nh_w, pos_w, st_w, pw1, ws);
  k_deg<<<(NE + 255)/256, 256, 0, stream>>>(h_id, t_id, ws);
  k_prep_nodes<<<(NTOT + 255)/256, 256, 0, stream>>>(topic, ws);
  k_dde_scatter<<<(NE + 255)/256, 256, 0, stream>>>(h_id, t_id, 0, 2, ws);
  k_dde_scale  <<<(NTOT + 255)/256, 256, 0, stream>>>(2, O_INVF, ws);
  k_dde_scatter<<<(NE + 255)/256, 256, 0, stream>>>(h_id, t_id, 2, 4, ws);
  k_dde_scale  <<<(NTOT + 255)/256, 256, 0, stream>>>(4, O_INVF, ws);
  k_dde_scatter<<<(NE + 255)/256, 256, 0, stream>>>(t_id, h_id, 0, 6, ws);
  k_dde_scale  <<<(NTOT + 255)/256, 256, 0, stream>>>(6, O_INVR, ws);
  k_dde_scatter<<<(NE + 255)/256, 256, 0, stream>>>(t_id, h_id, 6, 8, ws);
  k_dde_scale  <<<(NTOT + 255)/256, 256, 0, stream>>>(8, O_INVR, ws);
  k_adj<<<(NE + 255)/256, 256, 0, stream>>>(tids, twts, ws);
  k_motif_gnn<<<1, 256, 0, stream>>>(mo, gsw, gsb, gmw, gmb, ws);
  k_gate_cvec<<<1, 256, 0, stream>>>(q, gate_w, gate_b, pw1, pb1, ws);
  k_nme<<<(NTOT*MDIM + 255)/256, 256, 0, stream>>>(nids, nwts, ws);
  k_edge_mfma<<<NE/64, 256, 0, stream>>>(h_id, r_id, t_id, ent, rel, nte, tids, twts,
                                         nh_b, pos_b, st_b, pw2, pb2, ws, out);
}

// Round 3
// 533.530 us; speedup vs baseline: 4.6941x; 1.5169x over previous
//
#include <hip/hip_runtime.h>
#include <hip/hip_bf16.h>

#define N_TEXT 80000
#define NTOT   100000
#define NE     200000
#define EMB    256
#define HID    256
#define VMOT   17
#define MDIM   64
#define KTOK   4

typedef unsigned short u16;
typedef unsigned int   u32;
typedef short short8 __attribute__((ext_vector_type(8)));
typedef float f32x4 __attribute__((ext_vector_type(4)));

// ---------------- workspace layout (float offsets) ----------------
#define O_INVF 0                    // [NTOT] counts -> inv
#define O_INVR (NTOT)
#define O_POS  (2*NTOT)             // [NTOT*10]
#define O_ADJ  (12*NTOT)            // [289] (pad 512)
#define O_HTB  (12*NTOT + 512)      // u16[17*64] = 544 floats (pad 576)
#define O_GATE (12*NTOT + 1088)     // [3] (pad 16)
#define O_CVEC (12*NTOT + 1104)     // [256]
#define O_NME  (12*NTOT + 1360)     // u16[NTOT*64] = NTOT*32 floats
#define O_WSW  (O_NME + NTOT*32)    // swizzled bf16 weights
#define ZERO_FLOATS (12*NTOT + 512)

// swizzled weight blob offsets (u16 units), chunk=32k x 256 cols = 8192 u16
#define OW_A 0
#define OW_B 163840
#define OW_C 172032
#define OW_D 253952
#define SZ_W 319488
#define GA 20480
#define GB 1024
#define GC 10240
#define GD 8192
#define GTOT (GA+GB+GC+GD)

__device__ __forceinline__ u16 f2b(float f) {   // fp32 -> bf16 RNE
  unsigned u = __float_as_uint(f);
  return (u16)((u + 0x7fffu + ((u >> 16) & 1u)) >> 16);
}
__device__ __forceinline__ float b2f(u16 v) {
  return __uint_as_float(((unsigned)v) << 16);
}
__device__ __forceinline__ short8 pack8(const float* f) {
  short8 v;
#pragma unroll
  for (int j = 0; j < 8; j++) v[j] = (short)f2b(f[j]);
  return v;
}

// ---------------- small kernels ----------------
__global__ void k_zero(float* ws, int n) {
  int i = blockIdx.x * blockDim.x + threadIdx.x;
  if (i < n) ws[i] = 0.f;
}

// swizzled bf16 weight pack: blob order (chunk c, wave w, nt, lane ln, j)
// col = w*64 + nt*16 + (ln&15), k = c*32 + (ln>>4)*8 + j
__global__ void k_prep_w(const float* __restrict__ nh_w, const float* __restrict__ pos_w,
                         const float* __restrict__ st_w, const float* __restrict__ pw1,
                         float* __restrict__ ws) {
  int g = blockIdx.x * blockDim.x + threadIdx.x;
  if (g >= GTOT) return;
  int l, phase;
  if (g < GA) { l = g; phase = 0; }
  else if (g < GA + GB) { l = g - GA; phase = 1; }
  else if (g < GA + GB + GC) { l = g - GA - GB; phase = 2; }
  else { l = g - GA - GB - GC; phase = 3; }
  int c = l >> 10, r = l & 1023;
  int w = r >> 8, nt = (r >> 6) & 3, ln = r & 63;
  int col = w*64 + nt*16 + (ln & 15);
  int k0  = c*32 + ((ln >> 4) << 3);
  float f[8];
#pragma unroll
  for (int j = 0; j < 8; j++) {
    int k = k0 + j;
    float v = 0.f;
    if (phase == 0)      v = nh_w[k*256 + col];
    else if (phase == 1) { if (k < 10) v = pos_w[k*256 + col];
                           else if (k >= 16 && k < 26) v = pos_w[(k-6)*256 + col]; }
    else if (phase == 2) v = st_w[k*256 + col];
    else                 v = pw1[(256 + k)*256 + col];
    f[j] = v;
  }
  ((short8*)((u16*)(ws + O_WSW)))[g] = pack8(f);
}

// deg counts + DDE round-1 scatter (topic is ~1% nonzero -> zero-skip)
__global__ void k_deg_dde1(const int* __restrict__ h_id, const int* __restrict__ t_id,
                           const float* __restrict__ topic, float* __restrict__ ws) {
  int e = blockIdx.x * blockDim.x + threadIdx.x;
  if (e >= NE) return;
  int h = h_id[e], t = t_id[e];
  atomicAdd(&ws[O_INVF + t], 1.0f);
  atomicAdd(&ws[O_INVR + h], 1.0f);
  float hx = topic[2*h], hy = topic[2*h + 1];
  float tx = topic[2*t], ty = topic[2*t + 1];
  if (hx != 0.f) atomicAdd(&ws[O_POS + t*10 + 2], hx);
  if (hy != 0.f) atomicAdd(&ws[O_POS + t*10 + 3], hy);
  if (tx != 0.f) atomicAdd(&ws[O_POS + h*10 + 6], tx);
  if (ty != 0.f) atomicAdd(&ws[O_POS + h*10 + 7], ty);
}

// finalize inv, write topic cols, scale round-1 cols (-> h1 fwd/rev final)
__global__ void k_prep_nodes(const float* __restrict__ topic, float* __restrict__ ws) {
  int n = blockIdx.x * blockDim.x + threadIdx.x;
  if (n >= NTOT) return;
  float invf = 1.0f / fmaxf(ws[O_INVF + n], 1.0f);
  float invr = 1.0f / fmaxf(ws[O_INVR + n], 1.0f);
  ws[O_INVF + n] = invf;
  ws[O_INVR + n] = invr;
  float* p = &ws[O_POS + n*10];
  p[0] = topic[2*n]; p[1] = topic[2*n + 1];
  p[2] *= invf; p[3] *= invf;
  p[6] *= invr; p[7] *= invr;
}

// DDE round-2 scatter (reads scaled round-1)
__global__ void k_dde2(const int* __restrict__ h_id, const int* __restrict__ t_id,
                       float* __restrict__ ws) {
  int e = blockIdx.x * blockDim.x + threadIdx.x;
  if (e >= NE) return;
  int h = h_id[e], t = t_id[e];
  float a = ws[O_POS + h*10 + 2], b = ws[O_POS + h*10 + 3];
  float c = ws[O_POS + t*10 + 6], d = ws[O_POS + t*10 + 7];
  if (a != 0.f) atomicAdd(&ws[O_POS + t*10 + 4], a);
  if (b != 0.f) atomicAdd(&ws[O_POS + t*10 + 5], b);
  if (c != 0.f) atomicAdd(&ws[O_POS + h*10 + 8], c);
  if (d != 0.f) atomicAdd(&ws[O_POS + h*10 + 9], d);
}

__global__ void k_dde2_scale(float* __restrict__ ws) {
  int n = blockIdx.x * blockDim.x + threadIdx.x;
  if (n >= NTOT) return;
  float invf = ws[O_INVF + n], invr = ws[O_INVR + n];
  float* p = &ws[O_POS + n*10];
  p[4] *= invf; p[5] *= invf;
  p[8] *= invr; p[9] *= invr;
}

__global__ void k_adj(const int* __restrict__ tids, const float* __restrict__ twts,
                      float* __restrict__ ws) {
  __shared__ float sadj[4*304];   // per-wave copies to cut contention
  for (int i = threadIdx.x; i < 4*304; i += blockDim.x) sadj[i] = 0.f;
  __syncthreads();
  int wbase = (threadIdx.x >> 6) * 304;
  int e = blockIdx.x * blockDim.x + threadIdx.x;
  if (e < NE) {
    int id[KTOK]; float w[KTOK];
#pragma unroll
    for (int k = 0; k < KTOK; k++) { id[k] = tids[e*KTOK + k]; w[k] = twts[e*KTOK + k]; }
#pragma unroll
    for (int i = 0; i < KTOK; i++)
#pragma unroll
      for (int j = 0; j < KTOK; j++) {
        float c = w[i] * w[j];
        if (id[i] > 0 && id[j] > 0 && c > 0.f)
          atomicAdd(&sadj[wbase + id[i]*VMOT + id[j]], c);
      }
  }
  __syncthreads();
  for (int i = threadIdx.x; i < VMOT*VMOT; i += blockDim.x) {
    float v = sadj[i] + sadj[304 + i] + sadj[608 + i] + sadj[912 + i];
    if (v != 0.f) atomicAdd(&ws[O_ADJ + i], v);
  }
}

// fused: block 0 = motif GNN (-> bf16 ht), block 1 = gate + cvec
__global__ void k_motif_gate(const float* __restrict__ mo, const float* __restrict__ gsw,
                             const float* __restrict__ gsb, const float* __restrict__ gmw,
                             const float* __restrict__ gmb, const float* __restrict__ q,
                             const float* __restrict__ gate_w, const float* __restrict__ gate_b,
                             const float* __restrict__ pw1, const float* __restrict__ pb1,
                             float* __restrict__ ws) {
  int t = threadIdx.x;
  if (blockIdx.x == 0) {
    __shared__ float A[VMOT*VMOT];
    __shared__ float Bm[VMOT*VMOT];
    __shared__ float inv_row[VMOT];
    __shared__ float smo[VMOT*MDIM];
    __shared__ float sm[VMOT*MDIM];
    for (int i = t; i < VMOT*VMOT; i += blockDim.x) A[i] = ws[O_ADJ + i];
    for (int i = t; i < VMOT*MDIM; i += blockDim.x) smo[i] = mo[i];
    __syncthreads();
    for (int i = t; i < VMOT*VMOT; i += blockDim.x) {
      int r = i / VMOT, c = i % VMOT;
      float v = 0.5f * (A[i] + A[c*VMOT + r]) + (r == c ? 1.f : 0.f);
      if (r == 0 || c == 0) v = (r == 0 && c == 0) ? 1.f : 0.f;
      Bm[i] = v;
    }
    __syncthreads();
    if (t < VMOT) {
      float s = 0.f;
      for (int c = 0; c < VMOT; c++) s += Bm[t*VMOT + c];
      inv_row[t] = 1.f / fmaxf(s, 1e-8f);
    }
    __syncthreads();
    for (int i = t; i < VMOT*MDIM; i += blockDim.x) {
      int v = i / MDIM, d = i % MDIM;
      float s = 0.f;
      for (int u = 0; u < VMOT; u++) s += Bm[v*VMOT + u] * smo[u*MDIM + d];
      sm[i] = s * inv_row[v];
    }
    __syncthreads();
    for (int i = t; i < VMOT*MDIM; i += blockDim.x) {
      int v = i / MDIM, d = i % MDIM;
      float a = gsb[d] + gmb[d];
      for (int m = 0; m < MDIM; m++)
        a += smo[v*MDIM + m] * gsw[m*MDIM + d] + sm[v*MDIM + m] * gmw[m*MDIM + d];
      ((u16*)(ws + O_HTB))[i] = f2b(smo[i] + fmaxf(a, 0.f));
    }
  } else {
    __shared__ float sq[EMB];
    __shared__ float red[3];
    sq[t] = q[t];
    if (t < 3) red[t] = 0.f;
    __syncthreads();
    float s = pb1[t];
    for (int i = 0; i < EMB; i++) s += sq[i] * pw1[i*HID + t];
    ws[O_CVEC + t] = s;
    atomicAdd(&red[0], sq[t] * gate_w[t*3 + 0]);
    atomicAdd(&red[1], sq[t] * gate_w[t*3 + 1]);
    atomicAdd(&red[2], sq[t] * gate_w[t*3 + 2]);
    __syncthreads();
    if (t == 0) {
      float l0 = red[0] + gate_b[0], l1 = red[1] + gate_b[1], l2 = red[2] + gate_b[2];
      float mx = fmaxf(l0, fmaxf(l1, l2));
      float e0 = expf(l0 - mx), e1 = expf(l1 - mx), e2 = expf(l2 - mx);
      float inv = 1.f / (e0 + e1 + e2);
      ws[O_GATE + 0] = e0 * inv; ws[O_GATE + 1] = e1 * inv; ws[O_GATE + 2] = e2 * inv;
    }
  }
}

// node motif emb -> bf16; thread per (node, 8-dim group) for coalesced stores
__global__ void k_nme(const int* __restrict__ nids, const float* __restrict__ nwts,
                      float* __restrict__ ws) {
  __shared__ u16 sht[VMOT*MDIM];
  for (int i = threadIdx.x; i < (VMOT*MDIM)/2; i += blockDim.x)
    ((u32*)sht)[i] = ((const u32*)(ws + O_HTB))[i];
  __syncthreads();
  int gid = blockIdx.x * blockDim.x + threadIdx.x;
  if (gid >= NTOT * 8) return;
  int n = gid >> 3, d0 = (gid & 7) * 8;
  int4   iv = ((const int4*)nids)[n];
  float4 wv = ((const float4*)nwts)[n];
  int   id[4] = {iv.x, iv.y, iv.z, iv.w};
  float w[4]  = {wv.x, wv.y, wv.z, wv.w};
  float f[8];
#pragma unroll
  for (int j = 0; j < 8; j++) {
    float s = 0.f;
#pragma unroll
    for (int k = 0; k < 4; k++) s += w[k] * b2f(sht[id[k]*MDIM + d0 + j]);
    f[j] = s;
  }
  ((short8*)((u16*)(ws + O_NME)))[gid] = pack8(f);
}

// ---------------- MFMA edge kernel ----------------
// 64 edges x 256 cols per block, 4 waves; wave wv -> cols wv*64..+63.
// Unpadded blocked LDS: every wave b128 frag access covers a contiguous
// 1024B window of distinct 16B chunks -> conflict-free.
__global__ __launch_bounds__(256, 2) void k_edge_mfma(
    const int* __restrict__ h_id, const int* __restrict__ r_id, const int* __restrict__ t_id,
    const float* __restrict__ ent, const float* __restrict__ rel, const float* __restrict__ nte,
    const int* __restrict__ tids, const float* __restrict__ twts,
    const float* __restrict__ nh_b, const float* __restrict__ pos_b,
    const float* __restrict__ st_b, const float* __restrict__ pw2,
    const float* __restrict__ pb2,
    const float* __restrict__ ws, float* __restrict__ out) {
  __shared__ __align__(16) u16 sX[64*32];      // 4 KB  (chunk: 64 edges x 32 k)
  __shared__ __align__(16) u16 sW[8192];       // 16 KB (chunk: 256 cols x 32 k, frag order)
  __shared__ __align__(16) u16 sF[8*64*32];    // 32 KB (8 k-blocks of fused acts)
  __shared__ float sOut[64];
  __shared__ int sh[64], stt[64], sr[64];

  const int tid = threadIdx.x;
  const int wv = tid >> 6, ln = tid & 63;
  const int lm = ln & 15, lq = ln >> 4;
  const int cb = wv * 64;
  const int e0 = blockIdx.x * 64;
  const int srow = tid >> 2, sks = tid & 3;    // staging: row, 8-k segment

  if (tid < 64) {
    sh[tid]  = h_id[e0 + tid];
    stt[tid] = t_id[e0 + tid];
    sr[tid]  = r_id[e0 + tid];
    sOut[tid] = 0.f;
  }
  const float g0 = ws[O_GATE + 0], g1 = ws[O_GATE + 1], g2 = ws[O_GATE + 2];
  const u16* Wsw = (const u16*)(ws + O_WSW);
  const u16* WA = Wsw + OW_A;
  const u16* WB = Wsw + OW_B;
  const u16* WC = Wsw + OW_C;
  const u16* WD = Wsw + OW_D;
  const u16* nmeb = (const u16*)(ws + O_NME);
  const u16* htb  = (const u16*)(ws + O_HTB);
  // triple-motif ids/wts for this thread's staging row (used in phase C)
  const int4   tiv = ((const int4*)tids)[e0 + srow];
  const float4 twv = ((const float4*)twts)[e0 + srow];
  __syncthreads();

  f32x4 acc[4][4];
  float fused[4][4][4];
#pragma unroll
  for (int mt = 0; mt < 4; mt++)
#pragma unroll
    for (int nt = 0; nt < 4; nt++) {
      acc[mt][nt] = (f32x4){0.f, 0.f, 0.f, 0.f};
#pragma unroll
      for (int r = 0; r < 4; r++) fused[mt][nt][r] = 0.f;
    }

#define LOADW(W, c)                                                      \
  { const u16* p = (W) + (c)*8192 + tid*8;                               \
    wreg[0] = *(const short8*)(p);                                       \
    wreg[1] = *(const short8*)(p + 2048);                                \
    wreg[2] = *(const short8*)(p + 4096);                                \
    wreg[3] = *(const short8*)(p + 6144); }

#define STOREW()                                                         \
  { *(short8*)&sW[tid*8]        = wreg[0];                               \
    *(short8*)&sW[2048 + tid*8] = wreg[1];                               \
    *(short8*)&sW[4096 + tid*8] = wreg[2];                               \
    *(short8*)&sW[6144 + tid*8] = wreg[3]; }

#define MFMA_STEP()                                                      \
  { short8 a[4], b[4];                                                   \
    _Pragma("unroll")                                                    \
    for (int mt = 0; mt < 4; mt++)                                       \
      a[mt] = *(const short8*)&sX[(mt*16 + lm)*32 + lq*8];               \
    _Pragma("unroll")                                                    \
    for (int nt = 0; nt < 4; nt++)                                       \
      b[nt] = *(const short8*)&sW[wv*2048 + nt*512 + ln*8];              \
    _Pragma("unroll")                                                    \
    for (int mt = 0; mt < 4; mt++)                                       \
      _Pragma("unroll")                                                  \
      for (int nt = 0; nt < 4; nt++)                                     \
        acc[mt][nt] = __builtin_amdgcn_mfma_f32_16x16x32_bf16(a[mt], b[nt], acc[mt][nt], 0, 0, 0); }

  short8 wreg[4];

  // ======== phase A: h_nbr, K=640 = [h_e[h]|h_e[t]|nme[h]|nme[t]] ========
  {
    float4 fa, fb; short8 xs;
    auto loadA = [&](int kc) {
      int kk = kc + sks*8;
      if (kk < 512) {
        int node = (kk < 256) ? sh[srow] : stt[srow];
        int k2 = kk & 255;
        const float* src = (node < N_TEXT) ? &ent[(size_t)node*256 + k2] : &nte[k2];
        fa = *(const float4*)src; fb = *(const float4*)(src + 4);
      } else {
        int node = (kk < 576) ? sh[srow] : stt[srow];
        xs = *(const short8*)&nmeb[node*64 + ((kk - 512) & 63)];
      }
    };
    loadA(0); LOADW(WA, 0);
    for (int c = 0; c < 20; c++) {
      if (c*32 < 512) {
        float f[8] = {fa.x, fa.y, fa.z, fa.w, fb.x, fb.y, fb.z, fb.w};
        *(short8*)&sX[srow*32 + sks*8] = pack8(f);
      } else {
        *(short8*)&sX[srow*32 + sks*8] = xs;
      }
      STOREW();
      __syncthreads();
      if (c < 19) { loadA((c+1)*32); LOADW(WA, c+1); }
      MFMA_STEP();
      __syncthreads();
    }
  }
#pragma unroll
  for (int nt = 0; nt < 4; nt++) {
    float bb = nh_b[cb + nt*16 + lm];
#pragma unroll
    for (int mt = 0; mt < 4; mt++)
#pragma unroll
      for (int r = 0; r < 4; r++) {
        fused[mt][nt][r] += g0 * fmaxf(acc[mt][nt][r] + bb, 0.f);
        acc[mt][nt][r] = 0.f;
      }
  }

  // ======== phase B: h_pos, K=32 = [pos[h](10) pad6 | pos[t](10) pad6] ====
  {
    LOADW(WB, 0);
    int node_h = sh[srow], node_t = stt[srow];
    float f[8];
#pragma unroll
    for (int j = 0; j < 8; j++) {
      int kk = sks*8 + j;
      float v = 0.f;
      if (kk < 10) v = ws[O_POS + node_h*10 + kk];
      else if (kk >= 16 && kk < 26) v = ws[O_POS + node_t*10 + kk - 16];
      f[j] = v;
    }
    *(short8*)&sX[srow*32 + sks*8] = pack8(f);
    STOREW();
    __syncthreads();
    MFMA_STEP();
    __syncthreads();
  }
#pragma unroll
  for (int nt = 0; nt < 4; nt++) {
    float bb = pos_b[cb + nt*16 + lm];
#pragma unroll
    for (int mt = 0; mt < 4; mt++)
#pragma unroll
      for (int r = 0; r < 4; r++) {
        fused[mt][nt][r] += g1 * fmaxf(acc[mt][nt][r] + bb, 0.f);
        acc[mt][nt][r] = 0.f;
      }
  }

  // ======== phase C: h_str, K=320 = [rel[r] | triple_motif_emb] ========
  {
    float4 fa, fb; short8 hs0, hs1, hs2, hs3;
    auto loadC = [&](int kc) {
      int kk = kc + sks*8;
      if (kk < 256) {
        const float* src = &rel[(size_t)sr[srow]*256 + kk];
        fa = *(const float4*)src; fb = *(const float4*)(src + 4);
      } else {
        int d0 = kk - 256;
        hs0 = *(const short8*)&htb[tiv.x*64 + d0];
        hs1 = *(const short8*)&htb[tiv.y*64 + d0];
        hs2 = *(const short8*)&htb[tiv.z*64 + d0];
        hs3 = *(const short8*)&htb[tiv.w*64 + d0];
      }
    };
    loadC(0); LOADW(WC, 0);
    for (int c = 0; c < 10; c++) {
      if (c < 8) {
        float f[8] = {fa.x, fa.y, fa.z, fa.w, fb.x, fb.y, fb.z, fb.w};
        *(short8*)&sX[srow*32 + sks*8] = pack8(f);
      } else {
        float f[8];
#pragma unroll
        for (int j = 0; j < 8; j++)
          f[j] = twv.x * b2f((u16)hs0[j]) + twv.y * b2f((u16)hs1[j])
               + twv.z * b2f((u16)hs2[j]) + twv.w * b2f((u16)hs3[j]);
        *(short8*)&sX[srow*32 + sks*8] = pack8(f);
      }
      STOREW();
      __syncthreads();
      if (c < 9) { loadC((c+1)*32); LOADW(WC, c+1); }
      MFMA_STEP();
      __syncthreads();
    }
  }
#pragma unroll
  for (int nt = 0; nt < 4; nt++) {
    float bb = st_b[cb + nt*16 + lm];
#pragma unroll
    for (int mt = 0; mt < 4; mt++)
#pragma unroll
      for (int r = 0; r < 4; r++) {
        fused[mt][nt][r] += g2 * fmaxf(acc[mt][nt][r] + bb, 0.f);
        acc[mt][nt][r] = 0.f;
      }
  }

  // ---- transpose fused (C-layout regs) -> sF (blocked A-source layout) ----
  LOADW(WD, 0);   // prefetch phase-D chunk 0 while writing sF
#pragma unroll
  for (int mt = 0; mt < 4; mt++)
#pragma unroll
    for (int nt = 0; nt < 4; nt++) {
      int col = cb + nt*16 + lm;
      int base = (col >> 5)*2048 + (col & 31);
#pragma unroll
      for (int r = 0; r < 4; r++)
        sF[base + (mt*16 + lq*4 + r)*32] = f2b(fused[mt][nt][r]);
    }

  // ======== phase D: hidden = fused @ pw1[256:512] ========
  for (int c = 0; c < 8; c++) {
    STOREW();
    __syncthreads();
    if (c < 7) LOADW(WD, c+1);
    {
      short8 a[4], b[4];
#pragma unroll
      for (int mt = 0; mt < 4; mt++)
        a[mt] = *(const short8*)&sF[c*2048 + (mt*16 + lm)*32 + lq*8];
#pragma unroll
      for (int nt = 0; nt < 4; nt++)
        b[nt] = *(const short8*)&sW[wv*2048 + nt*512 + ln*8];
#pragma unroll
      for (int mt = 0; mt < 4; mt++)
#pragma unroll
        for (int nt = 0; nt < 4; nt++)
          acc[mt][nt] = __builtin_amdgcn_mfma_f32_16x16x32_bf16(a[mt], b[nt], acc[mt][nt], 0, 0, 0);
    }
    __syncthreads();
  }

  // ======== epilogue: out = relu(hidden + cvec) @ pw2 + pb2 ========
  {
    float cv[4], p2[4];
#pragma unroll
    for (int nt = 0; nt < 4; nt++) {
      int col = cb + nt*16 + lm;
      cv[nt] = ws[O_CVEC + col];
      p2[nt] = pw2[col];
    }
#pragma unroll
    for (int mt = 0; mt < 4; mt++)
#pragma unroll
      for (int r = 0; r < 4; r++) {
        float s = 0.f;
#pragma unroll
        for (int nt = 0; nt < 4; nt++)
          s += fmaxf(acc[mt][nt][r] + cv[nt], 0.f) * p2[nt];
#pragma unroll
        for (int off = 1; off < 16; off <<= 1)
          s += __shfl_xor(s, off, 64);
        if (lm == 0) atomicAdd(&sOut[mt*16 + lq*4 + r], s);
      }
  }
  __syncthreads();
  if (tid < 64) out[e0 + tid] = sOut[tid] + pb2[0];
#undef LOADW
#undef STOREW
#undef MFMA_STEP
}

// ---------------- launch ----------------
extern "C" void kernel_launch(void* const* d_in, const int* in_sizes, int n_in,
                              void* d_out, int out_size, void* d_ws, size_t ws_size,
                              hipStream_t stream) {
  (void)in_sizes; (void)n_in; (void)out_size; (void)ws_size;
  const int*   h_id   = (const int*)  d_in[0];
  const int*   r_id   = (const int*)  d_in[1];
  const int*   t_id   = (const int*)  d_in[2];
  const float* q      = (const float*)d_in[3];
  const float* ent    = (const float*)d_in[4];
  const float* rel    = (const float*)d_in[6];
  const float* topic  = (const float*)d_in[7];
  const int*   nids   = (const int*)  d_in[8];
  const float* nwts   = (const float*)d_in[9];
  const int*   tids   = (const int*)  d_in[10];
  const float* twts   = (const float*)d_in[11];
  const float* nte    = (const float*)d_in[12];
  const float* mo     = (const float*)d_in[13];
  const float* gsw    = (const float*)d_in[14];
  const float* gsb    = (const float*)d_in[15];
  const float* gmw    = (const float*)d_in[16];
  const float* gmb    = (const float*)d_in[17];
  const float* nh_w   = (const float*)d_in[18];
  const float* nh_b   = (const float*)d_in[19];
  const float* pos_w  = (const float*)d_in[20];
  const float* pos_b  = (const float*)d_in[21];
  const float* st_w   = (const float*)d_in[22];
  const float* st_b   = (const float*)d_in[23];
  const float* gate_w = (const float*)d_in[24];
  const float* gate_b = (const float*)d_in[25];
  const float* pw1    = (const float*)d_in[26];
  const float* pb1    = (const float*)d_in[27];
  const float* pw2    = (const float*)d_in[28];
  const float* pb2    = (const float*)d_in[29];
  float* ws  = (float*)d_ws;
  float* out = (float*)d_out;

  k_zero<<<(ZERO_FLOATS + 255)/256, 256, 0, stream>>>(ws, ZERO_FLOATS);
  k_prep_w<<<(GTOT + 255)/256, 256, 0, stream>>>(nh_w, pos_w, st_w, pw1, ws);
  k_deg_dde1<<<(NE + 255)/256, 256, 0, stream>>>(h_id, t_id, topic, ws);
  k_prep_nodes<<<(NTOT + 255)/256, 256, 0, stream>>>(topic, ws);
  k_dde2<<<(NE + 255)/256, 256, 0, stream>>>(h_id, t_id, ws);
  k_dde2_scale<<<(NTOT + 255)/256, 256, 0, stream>>>(ws);
  k_adj<<<(NE + 255)/256, 256, 0, stream>>>(tids, twts, ws);
  k_motif_gate<<<2, 256, 0, stream>>>(mo, gsw, gsb, gmw, gmb, q, gate_w, gate_b, pw1, pb1, ws);
  k_nme<<<(NTOT*8 + 255)/256, 256, 0, stream>>>(nids, nwts, ws);
  k_edge_mfma<<<NE/64, 256, 0, stream>>>(h_id, r_id, t_id, ent, rel, nte, tids, twts,
                                         nh_b, pos_b, st_b, pw2, pb2, ws, out);
}